// Round 15
// baseline (205.878 us; speedup 1.0000x reference)
//
#include <hip/hip_runtime.h>
#include <math.h>

#define B_   128
#define R_   1152
#define C_   16
#define O_   16
#define RS_  128
#define RCH_ 9             // R_/RS_

// ws float offsets
#define WS_SP   0          // RS_*32768 = 4194304
#define WS_V    4194304    // 32768
#define WS_BLOG 4227072    // 18432
#define WS_WT   4245504    // 2359296 (Wt4[r*512 + d*64 + co4])

__device__ __forceinline__ float squashf(float s) {
    return s * fabsf(s) / (1.0f + s * s);
}

// ---------- T: Wt4[r*512 + d*64 + co4] = W4[r*512 + co4*8 + d]  (pitch-65 LDS swizzle)
__global__ __launch_bounds__(512) void wtrans_k(const float* __restrict__ W,
                                                float* __restrict__ wt) {
    const int r = blockIdx.x;
    const int t = threadIdx.x;
    __shared__ float4 sh[520];
    const float4* __restrict__ W4 = (const float4*)W;
    float4* __restrict__ Wt4 = (float4*)wt;

    sh[(t & 7) * 65 + (t >> 3)] = W4[r * 512 + t];     // t = co4*8 + d
    __syncthreads();
    Wt4[r * 512 + t] = sh[(t >> 6) * 65 + (t & 63)];   // t = d*64 + co4
}

// ---------- G: sp[rs][b][co] = sum_{r in chunk,i} x[b,r,i]*cw[r,c]*W[r,co,i]
// grid (8 bt x 16 b, RS_ rs of 9 r) x 256 -> 1024 blocks = 4/CU (16 waves/CU).
// W fragments streamed coalesced from Wt (lane-stride 16 B, L2-served).
// FIRST: cw = 1/R exactly (iter 0), prepass skipped.
template <bool FIRST>
__global__ __launch_bounds__(256) void gemm_s_k(const float* __restrict__ x,
                                                const float* __restrict__ wt,
                                                const float* __restrict__ blog,
                                                float* __restrict__ sp) {
    const int bt  = blockIdx.x;
    const int rs  = blockIdx.y;
    const int t   = threadIdx.x;
    const int co4 = t & 63;
    const int b4  = t >> 6;
    const int c   = co4 >> 2;
    const int r0  = rs * RCH_;

    __shared__ float4 xl4[288];         // 16 b x 9 r x 2 f4 = 4.6 KB
    __shared__ float4 part[16];
    __shared__ float  colinv[16];
    __shared__ float  cwl[RCH_ * 16];   // 144

    const float4* __restrict__ X4  = (const float4*)x;
    const float4* __restrict__ Wt4 = (const float4*)wt;

    // stage x tile
    {
        const int u = t;
        if (u < 288) {
            const int bl = u / 18, rem = u % 18;
            xl4[u] = X4[((bt * 16 + bl) * R_ + r0) * 2 + rem];
        }
    }
    {
        const int u = t + 256;          // 256..287 handled above? no: t<288 covers 0..255; add tail
    }
    if (t < 32) {                        // u = 256..287
        const int u = t + 256;
        const int bl = u / 18, rem = u % 18;
        xl4[u] = X4[((bt * 16 + bl) * R_ + r0) * 2 + rem];
    }

    // prepass: colinv[c] = 1 / sum_r exp(blog[r,c]); cwl = softmax rows
    if (!FIRST) {
        const float4* BL4 = (const float4*)blog;
        const int g = t & 3;
        float4 e4; e4.x = 0.f; e4.y = 0.f; e4.z = 0.f; e4.w = 0.f;
        #pragma unroll
        for (int i = 0; i < 18; ++i) {
            const float4 bv = BL4[i * 256 + t];
            e4.x += __expf(bv.x); e4.y += __expf(bv.y);
            e4.z += __expf(bv.z); e4.w += __expf(bv.w);
        }
        #pragma unroll
        for (int d = 4; d < 64; d <<= 1) {
            e4.x += __shfl_xor(e4.x, d); e4.y += __shfl_xor(e4.y, d);
            e4.z += __shfl_xor(e4.z, d); e4.w += __shfl_xor(e4.w, d);
        }
        if ((t & 63) < 4) part[(t >> 6) * 4 + g] = e4;
        __syncthreads();
        if (t < 4) {
            const float4 a = part[t], b = part[4 + t], cc4 = part[8 + t], d = part[12 + t];
            colinv[t * 4 + 0] = 1.0f / ((a.x + b.x) + (cc4.x + d.x));
            colinv[t * 4 + 1] = 1.0f / ((a.y + b.y) + (cc4.y + d.y));
            colinv[t * 4 + 2] = 1.0f / ((a.z + b.z) + (cc4.z + d.z));
            colinv[t * 4 + 3] = 1.0f / ((a.w + b.w) + (cc4.w + d.w));
        }
        __syncthreads();
        if (t < RCH_ * 16) {
            const int rl = t >> 4, cc = t & 15;
            cwl[t] = __expf(blog[(r0 + rl) * 16 + cc]) * colinv[cc];
        }
    }
    __syncthreads();

    float acc[4][4];
    #pragma unroll
    for (int j = 0; j < 4; ++j)
        #pragma unroll
        for (int q = 0; q < 4; ++q) acc[j][q] = 0.f;

    #pragma unroll
    for (int rr = 0; rr < RCH_; ++rr) {
        const float cwv = FIRST ? (1.0f / (float)R_) : cwl[rr * 16 + c];
        const float4* wp = Wt4 + ((size_t)(r0 + rr) << 9) + co4;   // lane-stride 16B
        const float4 w0 = wp[  0], w1 = wp[ 64], w2 = wp[128], w3 = wp[192];
        const float4 w4 = wp[256], w5 = wp[320], w6 = wp[384], w7 = wp[448];
        #pragma unroll
        for (int j = 0; j < 4; ++j) {
            const float4 xa = xl4[(b4 * 4 + j) * 18 + rr * 2];
            const float4 xb = xl4[(b4 * 4 + j) * 18 + rr * 2 + 1];
            const float d0 = w0.x*xa.x + w0.y*xa.y + w0.z*xa.z + w0.w*xa.w
                           + w1.x*xb.x + w1.y*xb.y + w1.z*xb.z + w1.w*xb.w;
            const float d1 = w2.x*xa.x + w2.y*xa.y + w2.z*xa.z + w2.w*xa.w
                           + w3.x*xb.x + w3.y*xb.y + w3.z*xb.z + w3.w*xb.w;
            const float d2 = w4.x*xa.x + w4.y*xa.y + w4.z*xa.z + w4.w*xa.w
                           + w5.x*xb.x + w5.y*xb.y + w5.z*xb.z + w5.w*xb.w;
            const float d3 = w6.x*xa.x + w6.y*xa.y + w6.z*xa.z + w6.w*xa.w
                           + w7.x*xb.x + w7.y*xb.y + w7.z*xb.z + w7.w*xb.w;
            acc[j][0] = fmaf(cwv, d0, acc[j][0]);
            acc[j][1] = fmaf(cwv, d1, acc[j][1]);
            acc[j][2] = fmaf(cwv, d2, acc[j][2]);
            acc[j][3] = fmaf(cwv, d3, acc[j][3]);
        }
    }

    float4* sp4 = (float4*)sp;
    #pragma unroll
    for (int j = 0; j < 4; ++j) {
        const int b = bt * 16 + b4 * 4 + j;
        float4 o4; o4.x = acc[j][0]; o4.y = acc[j][1]; o4.z = acc[j][2]; o4.w = acc[j][3];
        sp4[(rs * B_ + b) * 64 + co4] = o4;
    }
}

// ---------- R: v[b,co] = squash(sum_k sp[k][b][co]); grid 256 x 512, k-split x4 ----
__global__ __launch_bounds__(512) void reduce_squash_k(const float* __restrict__ sp,
                                                       float* __restrict__ outv) {
    const int t   = threadIdx.x;
    const int li  = t & 127;
    const int kq  = t >> 7;               // 0..3 (32 slices each)
    const int idx = blockIdx.x * 128 + li;
    const float* p = sp + (size_t)kq * (RS_ / 4) * 32768 + idx;
    float a0 = 0.f, a1 = 0.f, a2 = 0.f, a3 = 0.f;
    #pragma unroll 4
    for (int k = 0; k < RS_ / 4; k += 4) {
        a0 += p[(k + 0) * 32768];
        a1 += p[(k + 1) * 32768];
        a2 += p[(k + 2) * 32768];
        a3 += p[(k + 3) * 32768];
    }
    __shared__ float red[512];
    red[t] = (a0 + a1) + (a2 + a3);
    __syncthreads();
    if (t < 128) {
        const float s = (red[t] + red[t + 128]) + (red[t + 256] + red[t + 384]);
        outv[idx] = squashf(s);
    }
}

// ---------- A: blog[r,c] (+)= (1/B) sum_{b,o} u_hat[b,r,co]*v[b,co] ----------
// grid 576 x 256 (4 waves: rr = w&1, half = w>>1; 2 r per block). W from Wt.
template <bool FIRST>
__global__ __launch_bounds__(256) void a_k(const float* __restrict__ x,
                                           const float* __restrict__ wt,
                                           const float* __restrict__ v,
                                           float* __restrict__ blog) {
    const int r0 = blockIdx.x * 2;
    const int t  = threadIdx.x;
    const int w  = t >> 6, lane = t & 63;
    const int rr = w & 1, half = w >> 1;
    const int co4 = lane, c = lane >> 2;

    __shared__ float4 xl[512];            // x[0:128][r0..r0+1][0:8] = 8 KB
    __shared__ float  red[64];
    const float4* __restrict__ X4  = (const float4*)x;
    const float4* __restrict__ V4  = (const float4*)v;
    const float4* __restrict__ Wt4 = (const float4*)wt;

    #pragma unroll
    for (int kk = 0; kk < 2; ++kk) {
        const int u = t + kk * 256;       // 0..511
        const int b = u >> 2, rem = u & 3;
        xl[u] = X4[(b * R_ + r0) * 2 + rem];
    }
    __syncthreads();

    float y[8][4];
    #pragma unroll
    for (int i = 0; i < 8; ++i)
        #pragma unroll
        for (int q = 0; q < 4; ++q) y[i][q] = 0.f;

    const int b0 = half * 64;
    #pragma unroll 4
    for (int bb = 0; bb < 64; ++bb) {
        const int b = b0 + bb;
        const float4 xa = xl[b * 4 + rr * 2];
        const float4 xb = xl[b * 4 + rr * 2 + 1];
        const float4 vv = V4[b * 64 + co4];
        const float xs[8] = {xa.x, xa.y, xa.z, xa.w, xb.x, xb.y, xb.z, xb.w};
        #pragma unroll
        for (int i = 0; i < 8; ++i) {
            y[i][0] = fmaf(xs[i], vv.x, y[i][0]);
            y[i][1] = fmaf(xs[i], vv.y, y[i][1]);
            y[i][2] = fmaf(xs[i], vv.z, y[i][2]);
            y[i][3] = fmaf(xs[i], vv.w, y[i][3]);
        }
    }

    const float4* wp = Wt4 + ((size_t)(r0 + rr) << 9) + co4;
    float part = 0.f;
    #pragma unroll
    for (int q = 0; q < 4; ++q) {
        const float4 w0 = wp[(2 * q) * 64];
        const float4 w1 = wp[(2 * q + 1) * 64];
        part += w0.x*y[0][q] + w0.y*y[1][q] + w0.z*y[2][q] + w0.w*y[3][q]
              + w1.x*y[4][q] + w1.y*y[5][q] + w1.z*y[6][q] + w1.w*y[7][q];
    }
    part += __shfl_xor(part, 1);
    part += __shfl_xor(part, 2);
    if ((lane & 3) == 0) red[w * 16 + c] = part;
    __syncthreads();
    if (t < 32) {
        const int rr2 = t >> 4, cc = t & 15;
        const float val = (red[rr2 * 16 + cc] + red[(rr2 + 2) * 16 + cc]) * (1.0f / (float)B_);
        const int idx = (r0 + rr2) * 16 + cc;
        blog[idx] = FIRST ? val : (blog[idx] + val);
    }
}

extern "C" void kernel_launch(void* const* d_in, const int* in_sizes, int n_in,
                              void* d_out, int out_size, void* d_ws, size_t ws_size,
                              hipStream_t stream) {
    const float* x = (const float*)d_in[0];   // [128,1152,8]
    const float* W = (const float*)d_in[1];   // [1,1152,16,16,8]
    float* out = (float*)d_out;               // [128,16,16]
    float* ws  = (float*)d_ws;                // ~26.4 MB used

    float* sp   = ws + WS_SP;
    float* v    = ws + WS_V;
    float* blog = ws + WS_BLOG;
    float* wt   = ws + WS_WT;

    // build Wt once (coalesced transpose)
    wtrans_k<<<R_, 512, 0, stream>>>(W, wt);

    // iter 0 (softmax(0) == 1/R exactly)
    gemm_s_k<true><<<dim3(8, RS_), 256, 0, stream>>>(x, wt, blog, sp);
    reduce_squash_k<<<256, 512, 0, stream>>>(sp, v);
    a_k<true><<<576, 256, 0, stream>>>(x, wt, v, blog);

    // iter 1
    gemm_s_k<false><<<dim3(8, RS_), 256, 0, stream>>>(x, wt, blog, sp);
    reduce_squash_k<<<256, 512, 0, stream>>>(sp, v);
    a_k<false><<<576, 256, 0, stream>>>(x, wt, v, blog);

    // iter 2
    gemm_s_k<false><<<dim3(8, RS_), 256, 0, stream>>>(x, wt, blog, sp);
    reduce_squash_k<<<256, 512, 0, stream>>>(sp, out);
}

// Round 16
// 180.127 us; speedup vs baseline: 1.1430x; 1.1430x over previous
//
#include <hip/hip_runtime.h>
#include <math.h>

#define B_   128
#define R_   1152
#define C_   16
#define O_   16
#define RS_  64
#define RCH_ 18            // R_/RS_

// ws float offsets
#define WS_SP   0          // RS_*32768 = 2097152
#define WS_V    2097152    // 32768
#define WS_BLOG 2129920    // 18432
#define WS_WT   2148352    // 2359296 (Wt4[r*512 + d*64 + co4])

__device__ __forceinline__ float squashf(float s) {
    return s * fabsf(s) / (1.0f + s * s);
}

// ---------- T: Wt4[r*512 + d*64 + co4] = W4[r*512 + co4*8 + d]  (pitch-65 LDS swizzle)
__global__ __launch_bounds__(512) void wtrans_k(const float* __restrict__ W,
                                                float* __restrict__ wt) {
    const int r = blockIdx.x;
    const int t = threadIdx.x;
    __shared__ float4 sh[520];
    const float4* __restrict__ W4 = (const float4*)W;
    float4* __restrict__ Wt4 = (float4*)wt;

    sh[(t & 7) * 65 + (t >> 3)] = W4[r * 512 + t];     // t = co4*8 + d
    __syncthreads();
    Wt4[r * 512 + t] = sh[(t >> 6) * 65 + (t & 63)];   // t = d*64 + co4
}

// ---------- G: sp[rs][b][co] = sum_{r in chunk,i} x[b,r,i]*cw[r,c]*W[r,co,i]
// grid (8 bt, RS_ rs) x 256. W fragments streamed coalesced from Wt.
// FIRST: cw = 1/R exactly (iter 0), no prepass. Else: column softmax prepass.
template <bool FIRST>
__global__ __launch_bounds__(256) void gemm_s_k(const float* __restrict__ x,
                                                const float* __restrict__ wt,
                                                const float* __restrict__ blog,
                                                float* __restrict__ sp) {
    const int bt  = blockIdx.x;
    const int rs  = blockIdx.y;
    const int t   = threadIdx.x;
    const int co4 = t & 63;
    const int b4  = t >> 6;
    const int c   = co4 >> 2;
    const int r0  = rs * RCH_;

    __shared__ float4 xl4[576];         // 16 b x 18 r x 2 f4 = 9 KB
    __shared__ float4 part[16];
    __shared__ float  colinv[16];
    __shared__ float  cwl[RCH_ * 16];   // 288

    const float4* __restrict__ X4  = (const float4*)x;
    const float4* __restrict__ Wt4 = (const float4*)wt;

    // stage x tile
    #pragma unroll
    for (int k = 0; k < 3; ++k) {
        const int u = t + k * 256;
        if (u < 576) {
            const int bl = u / 36, rem = u % 36;
            xl4[u] = X4[((bt * 16 + bl) * R_ + r0) * 2 + rem];
        }
    }

    // prepass: colinv[c] = 1 / sum_r exp(blog[r,c]); cwl = softmax rows (skip on iter 0)
    if (!FIRST) {
        const float4* BL4 = (const float4*)blog;
        const int g = t & 3;
        float4 e4; e4.x = 0.f; e4.y = 0.f; e4.z = 0.f; e4.w = 0.f;
        #pragma unroll
        for (int i = 0; i < 18; ++i) {
            const float4 bv = BL4[i * 256 + t];
            e4.x += __expf(bv.x); e4.y += __expf(bv.y);
            e4.z += __expf(bv.z); e4.w += __expf(bv.w);
        }
        #pragma unroll
        for (int d = 4; d < 64; d <<= 1) {
            e4.x += __shfl_xor(e4.x, d); e4.y += __shfl_xor(e4.y, d);
            e4.z += __shfl_xor(e4.z, d); e4.w += __shfl_xor(e4.w, d);
        }
        if ((t & 63) < 4) part[(t >> 6) * 4 + g] = e4;
        __syncthreads();
        if (t < 4) {
            const float4 a = part[t], b = part[4 + t], cc4 = part[8 + t], d = part[12 + t];
            colinv[t * 4 + 0] = 1.0f / ((a.x + b.x) + (cc4.x + d.x));
            colinv[t * 4 + 1] = 1.0f / ((a.y + b.y) + (cc4.y + d.y));
            colinv[t * 4 + 2] = 1.0f / ((a.z + b.z) + (cc4.z + d.z));
            colinv[t * 4 + 3] = 1.0f / ((a.w + b.w) + (cc4.w + d.w));
        }
        __syncthreads();
        for (int u2 = t; u2 < RCH_ * 16; u2 += 256) {
            const int rl = u2 >> 4, cc = u2 & 15;
            cwl[u2] = __expf(blog[(r0 + rl) * 16 + cc]) * colinv[cc];
        }
    }
    __syncthreads();

    float acc[4][4];
    #pragma unroll
    for (int j = 0; j < 4; ++j)
        #pragma unroll
        for (int q = 0; q < 4; ++q) acc[j][q] = 0.f;

    #pragma unroll 3
    for (int rr = 0; rr < RCH_; ++rr) {
        const float cwv = FIRST ? (1.0f / (float)R_) : cwl[rr * 16 + c];
        const float4* wp = Wt4 + ((size_t)(r0 + rr) << 9) + co4;   // lane-stride 16B
        const float4 w0 = wp[  0], w1 = wp[ 64], w2 = wp[128], w3 = wp[192];
        const float4 w4 = wp[256], w5 = wp[320], w6 = wp[384], w7 = wp[448];
        #pragma unroll
        for (int j = 0; j < 4; ++j) {
            const float4 xa = xl4[(b4 * 4 + j) * 36 + rr * 2];
            const float4 xb = xl4[(b4 * 4 + j) * 36 + rr * 2 + 1];
            const float d0 = w0.x*xa.x + w0.y*xa.y + w0.z*xa.z + w0.w*xa.w
                           + w1.x*xb.x + w1.y*xb.y + w1.z*xb.z + w1.w*xb.w;
            const float d1 = w2.x*xa.x + w2.y*xa.y + w2.z*xa.z + w2.w*xa.w
                           + w3.x*xb.x + w3.y*xb.y + w3.z*xb.z + w3.w*xb.w;
            const float d2 = w4.x*xa.x + w4.y*xa.y + w4.z*xa.z + w4.w*xa.w
                           + w5.x*xb.x + w5.y*xb.y + w5.z*xb.z + w5.w*xb.w;
            const float d3 = w6.x*xa.x + w6.y*xa.y + w6.z*xa.z + w6.w*xa.w
                           + w7.x*xb.x + w7.y*xb.y + w7.z*xb.z + w7.w*xb.w;
            acc[j][0] = fmaf(cwv, d0, acc[j][0]);
            acc[j][1] = fmaf(cwv, d1, acc[j][1]);
            acc[j][2] = fmaf(cwv, d2, acc[j][2]);
            acc[j][3] = fmaf(cwv, d3, acc[j][3]);
        }
    }

    float4* sp4 = (float4*)sp;
    #pragma unroll
    for (int j = 0; j < 4; ++j) {
        const int b = bt * 16 + b4 * 4 + j;
        float4 o4; o4.x = acc[j][0]; o4.y = acc[j][1]; o4.z = acc[j][2]; o4.w = acc[j][3];
        sp4[(rs * B_ + b) * 64 + co4] = o4;
    }
}

// ---------- R: v[b,co] = squash(sum_k sp[k][b][co]); grid 256 x 512, k-split x4 ----
__global__ __launch_bounds__(512) void reduce_squash_k(const float* __restrict__ sp,
                                                       float* __restrict__ outv) {
    const int t   = threadIdx.x;
    const int li  = t & 127;
    const int kq  = t >> 7;               // 0..3 (16 slices each)
    const int idx = blockIdx.x * 128 + li;
    const float* p = sp + (size_t)kq * 16 * 32768 + idx;
    float a0 = 0.f, a1 = 0.f, a2 = 0.f, a3 = 0.f;
    #pragma unroll
    for (int k = 0; k < 16; k += 4) {
        a0 += p[(k + 0) * 32768];
        a1 += p[(k + 1) * 32768];
        a2 += p[(k + 2) * 32768];
        a3 += p[(k + 3) * 32768];
    }
    __shared__ float red[512];
    red[t] = (a0 + a1) + (a2 + a3);
    __syncthreads();
    if (t < 128) {
        const float s = (red[t] + red[t + 128]) + (red[t + 256] + red[t + 384]);
        outv[idx] = squashf(s);
    }
}

// ---------- A: blog[r,c] (+)= (1/B) sum_{b,o} u_hat[b,r,co]*v[b,co] ----------
// grid 288 x 512 (8 waves: rr = w&3, half = w>>2). W from Wt (coalesced global).
template <bool FIRST>
__global__ __launch_bounds__(512) void a_k(const float* __restrict__ x,
                                           const float* __restrict__ wt,
                                           const float* __restrict__ v,
                                           float* __restrict__ blog) {
    const int r0 = blockIdx.x * 4;
    const int t  = threadIdx.x;
    const int w  = t >> 6, lane = t & 63;
    const int rr = w & 3, half = w >> 2;
    const int co4 = lane, c = lane >> 2;

    __shared__ float4 xl[128 * 8];        // 16 KB
    __shared__ float  red[128];
    const float4* __restrict__ X4  = (const float4*)x;
    const float4* __restrict__ V4  = (const float4*)v;
    const float4* __restrict__ Wt4 = (const float4*)wt;

    #pragma unroll
    for (int kk = 0; kk < 2; ++kk) {
        const int u = t + kk * 512;       // 0..1023
        const int b = u >> 3, rem = u & 7;
        xl[u] = X4[(b * R_ + r0) * 2 + rem];
    }
    __syncthreads();

    float y[8][4];
    #pragma unroll
    for (int i = 0; i < 8; ++i)
        #pragma unroll
        for (int q = 0; q < 4; ++q) y[i][q] = 0.f;

    const int b0 = half * 64;
    #pragma unroll 4
    for (int bb = 0; bb < 64; ++bb) {
        const int b = b0 + bb;
        const float4 xa = xl[b * 8 + rr * 2];
        const float4 xb = xl[b * 8 + rr * 2 + 1];
        const float4 vv = V4[b * 64 + co4];
        const float xs[8] = {xa.x, xa.y, xa.z, xa.w, xb.x, xb.y, xb.z, xb.w};
        #pragma unroll
        for (int i = 0; i < 8; ++i) {
            y[i][0] = fmaf(xs[i], vv.x, y[i][0]);
            y[i][1] = fmaf(xs[i], vv.y, y[i][1]);
            y[i][2] = fmaf(xs[i], vv.z, y[i][2]);
            y[i][3] = fmaf(xs[i], vv.w, y[i][3]);
        }
    }

    const float4* wp = Wt4 + ((size_t)(r0 + rr) << 9) + co4;
    float part = 0.f;
    #pragma unroll
    for (int q = 0; q < 4; ++q) {
        const float4 w0 = wp[(2 * q) * 64];
        const float4 w1 = wp[(2 * q + 1) * 64];
        part += w0.x*y[0][q] + w0.y*y[1][q] + w0.z*y[2][q] + w0.w*y[3][q]
              + w1.x*y[4][q] + w1.y*y[5][q] + w1.z*y[6][q] + w1.w*y[7][q];
    }
    part += __shfl_xor(part, 1);
    part += __shfl_xor(part, 2);
    if ((lane & 3) == 0) red[w * 16 + c] = part;
    __syncthreads();
    if (t < 64) {
        const int rr2 = t >> 4, cc = t & 15;
        const float val = (red[rr2 * 16 + cc] + red[(rr2 + 4) * 16 + cc]) * (1.0f / (float)B_);
        const int idx = (r0 + rr2) * 16 + cc;
        blog[idx] = FIRST ? val : (blog[idx] + val);
    }
}

extern "C" void kernel_launch(void* const* d_in, const int* in_sizes, int n_in,
                              void* d_out, int out_size, void* d_ws, size_t ws_size,
                              hipStream_t stream) {
    const float* x = (const float*)d_in[0];   // [128,1152,8]
    const float* W = (const float*)d_in[1];   // [1,1152,16,16,8]
    float* out = (float*)d_out;               // [128,16,16]
    float* ws  = (float*)d_ws;                // ~18 MB used

    float* sp   = ws + WS_SP;
    float* v    = ws + WS_V;
    float* blog = ws + WS_BLOG;
    float* wt   = ws + WS_WT;

    // build Wt once (coalesced transpose)
    wtrans_k<<<R_, 512, 0, stream>>>(W, wt);

    // iter 0 (softmax(0) == 1/R exactly)
    gemm_s_k<true><<<dim3(8, RS_), 256, 0, stream>>>(x, wt, blog, sp);
    reduce_squash_k<<<256, 512, 0, stream>>>(sp, v);
    a_k<true><<<288, 512, 0, stream>>>(x, wt, v, blog);

    // iter 1
    gemm_s_k<false><<<dim3(8, RS_), 256, 0, stream>>>(x, wt, blog, sp);
    reduce_squash_k<<<256, 512, 0, stream>>>(sp, v);
    a_k<false><<<288, 512, 0, stream>>>(x, wt, v, blog);

    // iter 2
    gemm_s_k<false><<<dim3(8, RS_), 256, 0, stream>>>(x, wt, blog, sp);
    reduce_squash_k<<<256, 512, 0, stream>>>(sp, out);
}